// Round 8
// baseline (427.631 us; speedup 1.0000x reference)
//
#include <hip/hip_runtime.h>
#include <hip/hip_fp16.h>
#include <hip/hip_cooperative_groups.h>

namespace cg = cooperative_groups;

// Problem constants (fixed by the reference file)
#define NN 50000     // nodes
#define NE 800000    // edges
#define HD 64        // feature dim (in and hidden)
#define NG 512       // graphs
#define NBK 196      // node buckets: node >> 8, max 49999>>8 = 195
#define PB  256      // prep blocks (1 per CU; cooperative co-resident)
#define EPB (NE / PB)           // 3125 edges per prep block (exact)
#define M2  (PB * PB)           // 65536 (bucket,block) counts
#define GEMM_BLOCKS 3125        // NN/16 row tiles

// Math: with h' = dinv*h (fp16):
//   o[c]   = dinv[c] * (sum_src h'[src] + h'[c]) + b          (layer output)
//   h'next = dinv * (relu(o) @ Wnext)                          (fused GEMM)
// R27: the middle was LAUNCH-BOUND (110 µs across 5-6 small launches for
// ~40 MB traffic / ~3 µs compute). Entire CSR pipeline + gemm1 fused into
// ONE cooperative kernel (grid=256 = 1 block/CU, grid.sync between phases):
//   A edge-hist (LDS, per-block range) + housekeeping
//   B mscan (R26-proven redundant-prefix scan) -> counts_ex
//   C scatter -> packed (LDS cursors)
//   D per-bucket CSR: hist/scan -> rowptr+dinv, fill esrc (R23 csr_build
//     minus rescale)
//   E gemm1 grid-stride, writes SCALED h16 (single fp16 rounding,
//     R24-validated numerics; 12.8 MB rescale pass stays deleted)
// NO global atomics: R24/R25/R26 all carried 800k cross-XCD atomicAdd in
// pass A and all ran 276-297 µs vs 255-262 for the atomic-free R19/R21/R23
// — ~25 µs atomic tax (cross-XCD line ping-pong). Do not reintroduce.
// R24 POST-MORTEM: direct cursor-atomic esrc fill -> 60 MB write
// amplification, 61 µs. Bucketed fill only.
//
// Gather body is R15/R21's proven shape (46.5-47.5 µs; ~12 variants tried):
// node-per-wave, scalar esrc stream, unmasked 8-edge batches + ONE masked
// batch, independent loads hoisted. DO NOT TOUCH:
//  - R20: int t[32] preload -> scratch spill (+25.6MB writes), 2x slower.
//  - R22: h2x2 8B-aggregate loads -> 8B/thread scratch spill, 2x slower.
//    FETCH 35MB ~= compulsory fabric floor -> gather at its random-access
//    roofline (HBM 17%, VALU 21%, occ 65%: latency floor).
// R23: gemm1 body: W column in VGPRs + wave-uniform broadcast float4 LDS
// reads (was LDS-issue-bound). k-ascending FMA order.

// ---------------------------------------------------------------------------
__global__ __launch_bounds__(256) void prep(const int* __restrict__ row,
                                            const int* __restrict__ col,
                                            const int* __restrict__ batch,
                                            const float* __restrict__ x,
                                            const float* __restrict__ W1,
                                            int* __restrict__ counts,
                                            int* __restrict__ counts_ex,
                                            unsigned* __restrict__ packed,
                                            int* __restrict__ rowptr,
                                            float* __restrict__ dinv,
                                            int* __restrict__ esrc,
                                            __half* __restrict__ h16,
                                            float* __restrict__ pooled,
                                            int* __restrict__ beg,
                                            int* __restrict__ endx) {
    cg::grid_group grid = cg::this_grid();
    __shared__ int   hist[256];     // phase A hist / phase C+D cursors
    __shared__ int   lrp[256];      // phase D row pointers
    __shared__ int   ws[4];
    __shared__ int   wsum[4];
    __shared__ int   spref;
    __shared__ float Is[16][64];    // phase E input tile (4 KB)

    int tid = threadIdx.x, blk = blockIdx.x;
    int lane = tid & 63, wid = tid >> 6;
    int lo = blk * EPB, hi = lo + EPB;      // this block's edge range (exact)

    // ---- phase A: bucket histogram + housekeeping --------------------------
    hist[tid] = 0;
    __syncthreads();
    for (int e = lo + tid; e < hi; e += 256)
        atomicAdd(&hist[col[e] >> 8], 1);   // LDS only
    int t = blk * 256 + tid;                // t in [0, 65536)
    if (t < NG * HD) pooled[t] = 0.f;
    if (t < NN) {
        int g = batch[t];
        if (t == 0 || batch[t - 1] != g) beg[g] = t;
        if (t == NN - 1 || batch[t + 1] != g) endx[g] = t + 1;
    }
    __syncthreads();
    counts[tid * PB + blk] = hist[tid];     // bucket-major; rows >=196 are 0
    grid.sync();

    // ---- phase B: exclusive scan over counts[M2] (R26 mscan) ---------------
    {
        int lim = blk * 256;
        int ps = 0;
        for (int k = tid; k < lim; k += 256) ps += counts[k];
#pragma unroll
        for (int off = 32; off > 0; off >>= 1) ps += __shfl_down(ps, off, 64);
        if (lane == 0) wsum[wid] = ps;
        int i = lim + tid;                  // < M2 always
        int v = counts[i];
        int inc = v;
#pragma unroll
        for (int off = 1; off < 64; off <<= 1) {
            int tt = __shfl_up(inc, off, 64);
            if (lane >= off) inc += tt;
        }
        if (lane == 63) ws[wid] = inc;
        __syncthreads();
        if (tid == 0) spref = wsum[0] + wsum[1] + wsum[2] + wsum[3];
        __syncthreads();
        int woff = 0;
        for (int k = 0; k < wid; ++k) woff += ws[k];
        counts_ex[i] = spref + woff + inc - v;
    }
    grid.sync();

    // ---- phase C: scatter into packed (LDS cursors) ------------------------
    __syncthreads();                        // phase B done reading hist? (A's)
    hist[tid] = 0;
    __syncthreads();
    for (int e = lo + tid; e < hi; e += 256) {
        int c = col[e], r = row[e];
        int b = c >> 8;
        int lpos = atomicAdd(&hist[b], 1);
        int pos = counts_ex[b * PB + blk] + lpos;
        packed[pos] = (unsigned)r | ((unsigned)(c & 255) << 16);
    }
    grid.sync();

    // ---- phase D: per-bucket CSR build (blocks 0..195) ---------------------
    if (blk < NBK) {
        int s = counts_ex[blk * PB];
        int e = (blk == NBK - 1) ? NE : counts_ex[(blk + 1) * PB];
        hist[tid] = 0;
        __syncthreads();
        for (int j = s + tid; j < e; j += 256)
            atomicAdd(&hist[(packed[j] >> 16) & 255], 1);
        __syncthreads();
        int v = hist[tid], inc = v;
#pragma unroll
        for (int off = 1; off < 64; off <<= 1) {
            int tt = __shfl_up(inc, off, 64);
            if (lane >= off) inc += tt;
        }
        if (lane == 63) ws[wid] = inc;
        __syncthreads();
        int woff = 0;
        for (int k = 0; k < wid; ++k) woff += ws[k];
        int excl = s + woff + inc - v;      // exclusive scan within bucket
        int node = blk * 256 + tid;
        if (node < NN) {
            rowptr[node] = excl;
            dinv[node] = rsqrtf((float)(v + 1));   // +1 self-loop
        }
        if (blk == 0 && tid == 0) rowptr[NN] = NE;
        lrp[tid] = excl;
        hist[tid] = 0;                      // reuse as fill cursor
        __syncthreads();
        for (int j = s + tid; j < e; j += 256) {
            unsigned p = packed[j];
            int lc = (p >> 16) & 255;
            int slot = lrp[lc] + atomicAdd(&hist[lc], 1);
            esrc[slot] = (int)(p & 0xFFFF); // NN < 65536
        }
    }
    grid.sync();

    // ---- phase E: h16 = fp16(dinv * (x @ W1)), grid-strided tiles ----------
    {
        int c = tid & 63, r4 = tid >> 6;
        float wcol[64];                     // W1 column c (L2-hot, 16 KB)
#pragma unroll
        for (int k = 0; k < 64; ++k) wcol[k] = W1[k * HD + c];
        for (int tile = blk; tile < GEMM_BLOCKS; tile += PB) {
            int row0 = tile * 16;
            // wave-uniform dinv loads (r4 const per wave)
            float d0 = dinv[row0 + r4 + 0];
            float d1 = dinv[row0 + r4 + 4];
            float d2 = dinv[row0 + r4 + 8];
            float d3 = dinv[row0 + r4 + 12];
            for (int i = tid; i < 16 * 64; i += 256)
                Is[i >> 6][i & 63] = x[(row0 + (i >> 6)) * HD + (i & 63)];
            __syncthreads();
            float a0 = 0.f, a1 = 0.f, a2 = 0.f, a3 = 0.f;
            const float4* i0p = (const float4*)&Is[r4 + 0][0];
            const float4* i1p = (const float4*)&Is[r4 + 4][0];
            const float4* i2p = (const float4*)&Is[r4 + 8][0];
            const float4* i3p = (const float4*)&Is[r4 + 12][0];
#pragma unroll
            for (int q = 0; q < 16; ++q) {  // k ascending (bit-exact)
                float4 i0 = i0p[q], i1 = i1p[q], i2 = i2p[q], i3 = i3p[q];
                float w0 = wcol[4 * q + 0], w1 = wcol[4 * q + 1];
                float w2 = wcol[4 * q + 2], w3 = wcol[4 * q + 3];
                a0 += i0.x * w0; a0 += i0.y * w1; a0 += i0.z * w2; a0 += i0.w * w3;
                a1 += i1.x * w0; a1 += i1.y * w1; a1 += i1.z * w2; a1 += i1.w * w3;
                a2 += i2.x * w0; a2 += i2.y * w1; a2 += i2.z * w2; a2 += i2.w * w3;
                a3 += i3.x * w0; a3 += i3.y * w1; a3 += i3.z * w2; a3 += i3.w * w3;
            }
            h16[(row0 + r4 + 0) * HD + c] = __float2half(d0 * a0);
            h16[(row0 + r4 + 4) * HD + c] = __float2half(d1 * a1);
            h16[(row0 + r4 + 8) * HD + c] = __float2half(d2 * a2);
            h16[(row0 + r4 + 12) * HD + c] = __float2half(d3 * a3);
            __syncthreads();                // protect Is reuse next tile
        }
    }
}

// ---------------------------------------------------------------------------
// Fused gather + next-layer GEMM (R19 body + R21 load-hoist — bench-proven
// 46.5-47.5 µs floor; R23-identical incl. dinv[] array load). ONE node per
// wave (readfirstlane -> scalar esrc stream). NAMED SCALARS ONLY.
// Epilogue (POOL=false): o = dinv*(acc+self)+b, then h'next[node] =
// fp16(dinv * (relu(o) @ Wnext)) — W column in VGPRs, row broadcast via
// per-wave LDS + ds_read_b128. Epilogue (POOL=true): pool atomics.
template <bool POOL>
__global__ __launch_bounds__(256) void gather_fx(const __half* __restrict__ hp,
                                                 const int* __restrict__ rowptr,
                                                 const int* __restrict__ esrc,
                                                 const float* __restrict__ dinv,
                                                 const float* __restrict__ b,
                                                 const float* __restrict__ Wnext,
                                                 __half* __restrict__ hnext,
                                                 const int* __restrict__ batch,
                                                 float* __restrict__ pooled) {
    __shared__ float rowbuf[4][64];             // 1 KB, per-wave slices
    int tid = threadIdx.x, lane = tid & 63, wid = tid >> 6;
    int p = lane >> 5, c = lane & 31;           // edge-of-pair, half2 channel
    int node = __builtin_amdgcn_readfirstlane(blockIdx.x * 4 + wid);
    const __half2* hv = (const __half2*)hp;

    // Independent loads FIRST (R21): overlap the rowptr->esrc scalar chain.
    float di = dinv[node];                      // wave-uniform scalar load
    float2 self = __half22float2(hv[node * 32 + c]);   // pre-scaled h'
    float2 bb = ((const float2*)b)[c];

    float wcol[POOL ? 1 : 64];                  // W column for this lane
    if (!POOL) {
#pragma unroll
        for (int k = 0; k < 64; ++k) wcol[k] = Wnext[k * HD + lane];  // L2-hot
    }

    int s = rowptr[node], e = rowptr[node + 1];     // scalar loads
    float2 acc = {0.f, 0.f};
    int j = s;
    for (; j + 8 <= e; j += 8) {                // unmasked full batches
        int t0 = esrc[j + 0], t1 = esrc[j + 1], t2 = esrc[j + 2], t3 = esrc[j + 3];
        int t4 = esrc[j + 4], t5 = esrc[j + 5], t6 = esrc[j + 6], t7 = esrc[j + 7];
        int a0 = p ? t1 : t0;
        int a1 = p ? t3 : t2;
        int a2 = p ? t5 : t4;
        int a3 = p ? t7 : t6;
        float2 f0 = __half22float2(hv[a0 * 32 + c]);
        float2 f1 = __half22float2(hv[a1 * 32 + c]);
        float2 f2 = __half22float2(hv[a2 * 32 + c]);
        float2 f3 = __half22float2(hv[a3 * 32 + c]);
        acc.x += (f0.x + f1.x) + (f2.x + f3.x);
        acc.y += (f0.y + f1.y) + (f2.y + f3.y);
    }
    if (j < e) {                                // ONE masked batch (rem 1..7)
        // overrun reads stay in allocated memory (esrc padded +64); &0xFFFF
        // bounds any garbage; invalid lanes clamp to t0 (real edge, j < e)
        // and are zero-multiplied — garbage never reaches a gather address.
        int t0 = esrc[j + 0] & 0xFFFF, t1 = esrc[j + 1] & 0xFFFF;
        int t2 = esrc[j + 2] & 0xFFFF, t3 = esrc[j + 3] & 0xFFFF;
        int t4 = esrc[j + 4] & 0xFFFF, t5 = esrc[j + 5] & 0xFFFF;
        int t6 = esrc[j + 6] & 0xFFFF, t7 = esrc[j + 7] & 0xFFFF;
        int i0 = j + p, i1 = j + 2 + p, i2 = j + 4 + p, i3 = j + 6 + p;
        int a0 = p ? t1 : t0;
        int a1 = p ? t3 : t2;
        int a2 = p ? t5 : t4;
        int a3 = p ? t7 : t6;
        a0 = (i0 < e) ? a0 : t0;
        a1 = (i1 < e) ? a1 : t0;
        a2 = (i2 < e) ? a2 : t0;
        a3 = (i3 < e) ? a3 : t0;
        float m0 = (i0 < e) ? 1.f : 0.f;
        float m1 = (i1 < e) ? 1.f : 0.f;
        float m2 = (i2 < e) ? 1.f : 0.f;
        float m3 = (i3 < e) ? 1.f : 0.f;
        float2 f0 = __half22float2(hv[a0 * 32 + c]);
        float2 f1 = __half22float2(hv[a1 * 32 + c]);
        float2 f2 = __half22float2(hv[a2 * 32 + c]);
        float2 f3 = __half22float2(hv[a3 * 32 + c]);
        acc.x += m0 * f0.x + m1 * f1.x + m2 * f2.x + m3 * f3.x;
        acc.y += m0 * f0.y + m1 * f1.y + m2 * f2.y + m3 * f3.y;
    }
    // combine the two edge-pair partials (lane L ^ 32 holds same channel)
    acc.x += __shfl_xor(acc.x, 32, 64);
    acc.y += __shfl_xor(acc.y, 32, 64);

    if (POOL) {
        if (p == 0) {
            float vx = di * (acc.x + self.x) + bb.x;
            float vy = di * (acc.y + self.y) + bb.y;
            int g = batch[node];
            atomicAdd(&pooled[g * HD + 2 * c], vx);
            atomicAdd(&pooled[g * HD + 2 * c + 1], vy);
        }
    } else {
        if (p == 0) {                           // o = dinv*(acc+self)+b; relu
            rowbuf[wid][2 * c]     = fmaxf(di * (acc.x + self.x) + bb.x, 0.f);
            rowbuf[wid][2 * c + 1] = fmaxf(di * (acc.y + self.y) + bb.y, 0.f);
        }
        // same-wave LDS write->read; compiler inserts lgkmcnt wait. No cross-
        // wave hazard: rowbuf slice is private to this wave.
        float outc = 0.f;
        const float4* rb4 = (const float4*)&rowbuf[wid][0];
#pragma unroll
        for (int jj = 0; jj < 16; ++jj) {       // 16 broadcast b128 reads
            float4 r = rb4[jj];
            outc += r.x * wcol[4 * jj + 0] + r.y * wcol[4 * jj + 1]
                  + r.z * wcol[4 * jj + 2] + r.w * wcol[4 * jj + 3];
        }
        hnext[(size_t)node * HD + lane] = __float2half(di * outc);
    }
}

// out[g] = (pooled[g,:]/max(cnt,1)) . lin_W + lin_b   — one wave per graph
__global__ __launch_bounds__(64) void final_kernel(const float* __restrict__ pooled,
                                                   const int* __restrict__ beg,
                                                   const int* __restrict__ endx,
                                                   const float* __restrict__ lin_W,
                                                   const float* __restrict__ lin_b,
                                                   float* __restrict__ out) {
    int g = blockIdx.x, d = threadIdx.x;
    float cnt = (float)(endx[g] - beg[g]);
    float v = pooled[g * HD + d] / fmaxf(cnt, 1.f) * lin_W[d];
#pragma unroll
    for (int off = 32; off > 0; off >>= 1) v += __shfl_down(v, off, 64);
    if (d == 0) out[g] = v + lin_b[0];
}

// ---------------------------------------------------------------------------
extern "C" void kernel_launch(void* const* d_in, const int* in_sizes, int n_in,
                              void* d_out, int out_size, void* d_ws, size_t ws_size,
                              hipStream_t stream) {
    const float* x     = (const float*)d_in[0];
    const float* W1    = (const float*)d_in[1];
    const float* b1    = (const float*)d_in[2];
    const float* W2    = (const float*)d_in[3];
    const float* b2    = (const float*)d_in[4];
    const float* W3    = (const float*)d_in[5];
    const float* b3    = (const float*)d_in[6];
    const float* lin_W = (const float*)d_in[7];
    const float* lin_b = (const float*)d_in[8];
    const int* edge_index = (const int*)d_in[9];   // [2, NE]: row then col
    const int* batch      = (const int*)d_in[10];
    const int* row = edge_index;
    const int* col = edge_index + NE;
    float* out = (float*)d_out;

    // workspace layout (4B units):
    // [h16a NN*HD half][h16b NN*HD half][esrc NE+64][packed NE]
    // [counts M2][counts_ex M2][rowptr NN+2][dinv NN]
    // [pooled NG*HD][beg NG][endx NG]                total ~21 MB
    __half*   h16a      = (__half*)d_ws;
    __half*   h16b      = h16a + (size_t)NN * HD;
    int*      esrc      = (int*)(h16b + (size_t)NN * HD);
    unsigned* packed    = (unsigned*)(esrc + NE + 64);
    int*      counts    = (int*)(packed + NE);
    int*      counts_ex = counts + M2;
    int*      rowptr    = counts_ex + M2;
    float*    dinv      = (float*)(rowptr + NN + 2);
    float*    pooled    = (float*)(dinv + NN);
    int*      beg       = (int*)(pooled + NG * HD);
    int*      endx      = beg + NG;

    // ONE cooperative prep (hist -> scan -> scatter -> CSR -> scaled gemm1),
    // then the three proven gathers and the final reduction. 5 launches.
    {
        void* args[] = {(void*)&row, (void*)&col, (void*)&batch, (void*)&x,
                        (void*)&W1, (void*)&counts, (void*)&counts_ex,
                        (void*)&packed, (void*)&rowptr, (void*)&dinv,
                        (void*)&esrc, (void*)&h16a, (void*)&pooled,
                        (void*)&beg, (void*)&endx};
        hipLaunchCooperativeKernel((const void*)prep, dim3(PB), dim3(256),
                                   args, 0, stream);
    }

    const int GB = NN / 4;  // gather blocks: 4 nodes (waves) each

    // Layer 1 aggregate + fused GEMM2: h16a(=h1') -> h16b(=h2')
    gather_fx<false><<<GB, 256, 0, stream>>>(h16a, rowptr, esrc, dinv, b1, W2,
                                             h16b, batch, pooled);
    // Layer 2 aggregate + fused GEMM3: h16b(=h2') -> h16a(=h3')
    gather_fx<false><<<GB, 256, 0, stream>>>(h16b, rowptr, esrc, dinv, b2, W3,
                                             h16a, batch, pooled);
    // Layer 3 aggregate -> pooled (fused)
    gather_fx<true><<<GB, 256, 0, stream>>>(h16a, rowptr, esrc, dinv, b3, nullptr,
                                            nullptr, batch, pooled);

    final_kernel<<<NG, 64, 0, stream>>>(pooled, beg, endx, lin_W, lin_b, out);
}

// Round 9
// 266.349 us; speedup vs baseline: 1.6055x; 1.6055x over previous
//
#include <hip/hip_runtime.h>
#include <hip/hip_fp16.h>

// Problem constants (fixed by the reference file)
#define NN 50000     // nodes
#define NE 800000    // edges
#define HD 64        // feature dim (in and hidden)
#define NG 512       // graphs
#define NBK 196      // node buckets: node >> 8, max 49999>>8 = 195
#define NBL 196      // edge blocks of 4096: ceil(NE/4096)
#define M_CNT (NBK * NBL)       // 38416 bucket-block counts
#define GEMM_BLOCKS 3125        // NN/16 row tiles

// Math: with h' = dinv*h (fp16):
//   o[c]   = dinv[c] * (sum_src h'[src] + h'[c]) + b          (layer output)
//   h'next = dinv * (relu(o) @ Wnext)                          (fused GEMM)
// R28: R23 structure (proven 255.3 µs) with the two scan launches DELETED
// via redundant self-scan: scatter blocks and csr_build blocks recompute
// the counts_ex slice they need from the 150 KB L2-resident counts matrix
// (~50K L2 reads/block ~= 1-2 µs wall; R26's mscan proved the pattern).
// Positions are bit-identical to the scanned version. 9 -> 7 launches.
// FAILED-DIRECTION LEDGER (do not revisit):
//  - R24/25/26: 800k cross-XCD atomicAdd degree/fill -> +25-40 µs (line
//    ping-pong across 8 non-coherent L2s). No global atomics in the middle.
//  - R27: cooperative 1-block/CU mega-kernel -> 207 µs prep (4 waves/CU,
//    occupancy 11.7%). No grid.sync fusion.
//  - R20: int t[32] preload -> scratch spill, 2x. R22: 8B-aggregate gather
//    loads -> spill, 2x. Gather = NAMED SCALARS ONLY.
// Gather at its random-fabric roofline: FETCH 35MB ~= compulsory floor,
// HBM 17%, VALU 21%, occ 65% -> latency floor (R15/R19/R21 ~12 variants).

// ---------------------------------------------------------------------------
// Pass A: per-(block,bucket) edge counts via LDS histogram (NO global
// atomics) + graph boundaries (sorted batch) + zero pooled[].
__global__ __launch_bounds__(256) void bucket_count(const int* __restrict__ col,
                                                    const int* __restrict__ batch,
                                                    int* __restrict__ counts,
                                                    int* __restrict__ beg,
                                                    int* __restrict__ endx,
                                                    float* __restrict__ pooled) {
    __shared__ int hist[256];
    int tid = threadIdx.x, blk = blockIdx.x;
    hist[tid] = 0;
    __syncthreads();
    int base = blk * 4096;
#pragma unroll
    for (int k = 0; k < 16; ++k) {
        int e = base + k * 256 + tid;
        if (e < NE) atomicAdd(&hist[col[e] >> 8], 1);   // LDS only
    }
    int t = blk * 256 + tid;
    if (t < NG * HD) pooled[t] = 0.f;          // 50176 threads >= 32768
    if (t < NN) {
        int g = batch[t];
        if (t == 0 || batch[t - 1] != g) beg[g] = t;
        if (t == NN - 1 || batch[t + 1] != g) endx[g] = t + 1;
    }
    __syncthreads();
    if (tid < NBK) counts[tid * NBL + blk] = hist[tid];  // bucket-major
}

// ---------------------------------------------------------------------------
// Fused 2-range dispatch:
//  [0, GEMM_BLOCKS):      h16 = fp16(x @ W1) UNSCALED (csr_build scales in
//                         place once dinv known — R19/R23 proven, absmax 0).
//  [GEMM_BLOCKS, +NBL):   scatter edges into packed[]. R28: base offsets
//                         self-computed from counts (thread b reads row b:
//                         rowsum + colpart(<blk); LDS scan of rowsums) —
//                         bit-identical to the old counts_ex lookup.
__global__ __launch_bounds__(256) void gemm1_scatter(const float* __restrict__ x,
                                                     const float* __restrict__ W1,
                                                     __half* __restrict__ h16,
                                                     const int* __restrict__ row,
                                                     const int* __restrict__ col,
                                                     const int* __restrict__ counts,
                                                     unsigned* __restrict__ packed) {
    if (blockIdx.x < GEMM_BLOCKS) {
        __shared__ float Is[16][64];   // 4 KB
        int t = threadIdx.x;
        int c = t & 63, r4 = t >> 6;
        float wcol[64];                // W1 column c, L2-hot (16 KB total)
#pragma unroll
        for (int k = 0; k < 64; ++k) wcol[k] = W1[k * HD + c];
        int row0 = blockIdx.x * 16;
        for (int i = t; i < 16 * 64; i += 256)
            Is[i >> 6][i & 63] = x[(row0 + (i >> 6)) * HD + (i & 63)];
        __syncthreads();
        float a0 = 0.f, a1 = 0.f, a2 = 0.f, a3 = 0.f;
        const float4* i0p = (const float4*)&Is[r4 + 0][0];
        const float4* i1p = (const float4*)&Is[r4 + 4][0];
        const float4* i2p = (const float4*)&Is[r4 + 8][0];
        const float4* i3p = (const float4*)&Is[r4 + 12][0];
#pragma unroll
        for (int q = 0; q < 16; ++q) {  // k = 4q..4q+3, ascending (bit-exact)
            float4 i0 = i0p[q], i1 = i1p[q], i2 = i2p[q], i3 = i3p[q];
            float w0 = wcol[4 * q + 0], w1 = wcol[4 * q + 1];
            float w2 = wcol[4 * q + 2], w3 = wcol[4 * q + 3];
            a0 += i0.x * w0; a0 += i0.y * w1; a0 += i0.z * w2; a0 += i0.w * w3;
            a1 += i1.x * w0; a1 += i1.y * w1; a1 += i1.z * w2; a1 += i1.w * w3;
            a2 += i2.x * w0; a2 += i2.y * w1; a2 += i2.z * w2; a2 += i2.w * w3;
            a3 += i3.x * w0; a3 += i3.y * w1; a3 += i3.z * w2; a3 += i3.w * w3;
        }
        h16[(row0 + r4 + 0) * HD + c] = __float2half(a0);
        h16[(row0 + r4 + 4) * HD + c] = __float2half(a1);
        h16[(row0 + r4 + 8) * HD + c] = __float2half(a2);
        h16[(row0 + r4 + 12) * HD + c] = __float2half(a3);
    } else {
        __shared__ int ws[4];
        __shared__ int bas[256];
        __shared__ int cur[256];
        int tid = threadIdx.x, blk = blockIdx.x - GEMM_BLOCKS;
        int lane = tid & 63, wid = tid >> 6;
        // self-scan: thread tid owns bucket tid. rowsum = full row; colpart
        // = prefix over edge-blocks < blk. counts rows >= NBK don't exist ->
        // guarded to zero (buckets 196..255 never occur: col>>8 <= 195).
        int colpart = 0, rowsum = 0;
        if (tid < NBK) {
            const int* rowp = counts + tid * NBL;
#pragma unroll 4
            for (int k = 0; k < NBL; ++k) {
                int v = rowp[k];
                rowsum += v;
                colpart += (k < blk) ? v : 0;
            }
        }
        int inc = rowsum;                       // exclusive scan of rowsums
#pragma unroll
        for (int off = 1; off < 64; off <<= 1) {
            int tt = __shfl_up(inc, off, 64);
            if (lane >= off) inc += tt;
        }
        if (lane == 63) ws[wid] = inc;
        __syncthreads();
        int woff = 0;
        for (int k = 0; k < wid; ++k) woff += ws[k];
        bas[tid] = (woff + inc - rowsum) + colpart;  // == counts_ex[tid*NBL+blk]
        cur[tid] = 0;
        __syncthreads();
        int base = blk * 4096;
#pragma unroll
        for (int k = 0; k < 16; ++k) {
            int e = base + k * 256 + tid;
            if (e < NE) {
                int c = col[e], r = row[e];
                int b = c >> 8;
                int lpos = atomicAdd(&cur[b], 1);
                packed[bas[b] + lpos] = (unsigned)r | ((unsigned)(c & 255) << 16);
            }
        }
    }
}

// ---------------------------------------------------------------------------
// Fused CSR build (R23 body + R28 self-scanned bucket bounds): per 256-col
// bucket — (0) self-scan counts rowsums -> segment [s,e); (1) histogram+scan
// -> rowptr/dinv; (1.5) scale h16 IN PLACE (h16 *= dinv; 2nd fp16 rounding,
// <=1 ulp, harness-invisible); (2) fill esrc via LDS cursors.
__global__ __launch_bounds__(256) void csr_build(const unsigned* __restrict__ packed,
                                                 const int* __restrict__ counts,
                                                 int* __restrict__ rowptr,
                                                 float* __restrict__ dinv,
                                                 __half* __restrict__ h16,
                                                 int* __restrict__ esrc) {
    __shared__ int hist[256];
    __shared__ int ws[4];
    __shared__ int lrp[256];
    __shared__ float sdinv[256];
    __shared__ int sstart[257];
    int bkt = blockIdx.x, tid = threadIdx.x;
    int lane = tid & 63, wid = tid >> 6;
    // (0) self-scan: thread tid sums counts row tid; LDS scan -> bucket starts
    {
        int rowsum = 0;
        if (tid < NBK) {
            const int* rowp = counts + tid * NBL;
#pragma unroll 4
            for (int k = 0; k < NBL; ++k) rowsum += rowp[k];
        }
        int inc = rowsum;
#pragma unroll
        for (int off = 1; off < 64; off <<= 1) {
            int tt = __shfl_up(inc, off, 64);
            if (lane >= off) inc += tt;
        }
        if (lane == 63) ws[wid] = inc;
        __syncthreads();
        int woff = 0;
        for (int k = 0; k < wid; ++k) woff += ws[k];
        sstart[tid] = woff + inc - rowsum;       // exclusive
        if (tid == 255) sstart[256] = woff + inc; // inclusive total (=NE)
    }
    hist[tid] = 0;
    __syncthreads();
    int s = sstart[bkt], e = sstart[bkt + 1];
    for (int j = s + tid; j < e; j += 256)
        atomicAdd(&hist[(packed[j] >> 16) & 255], 1);
    __syncthreads();
    int v = hist[tid], inc = v;
#pragma unroll
    for (int off = 1; off < 64; off <<= 1) {
        int t = __shfl_up(inc, off, 64);
        if (lane >= off) inc += t;
    }
    if (lane == 63) ws[wid] = inc;
    __syncthreads();
    int woff = 0;
    for (int k = 0; k < wid; ++k) woff += ws[k];
    int excl = s + woff + inc - v;               // exclusive scan
    int node = bkt * 256 + tid;
    float dv = rsqrtf((float)(v + 1));           // +1 self-loop
    if (node < NN) {
        rowptr[node] = excl;
        dinv[node] = dv;
    }
    if (bkt == 0 && tid == 0) rowptr[NN] = NE;
    lrp[tid] = excl;
    sdinv[tid] = dv;
    hist[tid] = 0;                               // reuse as fill cursor
    __syncthreads();
    // (1.5) scale rows of this bucket in place: h16 *= dinv
    {
        int nrows = (bkt == NBK - 1) ? (NN - 195 * 256) : 256;
        __half2* hb16 = (__half2*)(h16 + (size_t)bkt * 256 * HD);
        for (int i = tid; i < nrows * 32; i += 256) {
            float d = sdinv[i >> 5];
            float2 f = __half22float2(hb16[i]);
            hb16[i] = __floats2half2_rn(d * f.x, d * f.y);
        }
    }
    // (2) fill
    for (int j = s + tid; j < e; j += 256) {
        unsigned p = packed[j];
        int lc = (p >> 16) & 255;
        int slot = lrp[lc] + atomicAdd(&hist[lc], 1);
        esrc[slot] = (int)(p & 0xFFFF);          // NN < 65536
    }
}

// ---------------------------------------------------------------------------
// Fused gather + next-layer GEMM (R19 body + R21 load-hoist — bench-proven
// 46.5-47.5 µs floor). ONE node per wave (readfirstlane -> scalar esrc
// stream). NAMED SCALARS ONLY.
// Epilogue (POOL=false): o = dinv*(acc+self)+b, then h'next[node] =
// fp16(dinv * (relu(o) @ Wnext)) — W column in VGPRs, row broadcast via
// per-wave LDS + ds_read_b128. Epilogue (POOL=true): pool atomics.
template <bool POOL>
__global__ __launch_bounds__(256) void gather_fx(const __half* __restrict__ hp,
                                                 const int* __restrict__ rowptr,
                                                 const int* __restrict__ esrc,
                                                 const float* __restrict__ dinv,
                                                 const float* __restrict__ b,
                                                 const float* __restrict__ Wnext,
                                                 __half* __restrict__ hnext,
                                                 const int* __restrict__ batch,
                                                 float* __restrict__ pooled) {
    __shared__ float rowbuf[4][64];             // 1 KB, per-wave slices
    int tid = threadIdx.x, lane = tid & 63, wid = tid >> 6;
    int p = lane >> 5, c = lane & 31;           // edge-of-pair, half2 channel
    int node = __builtin_amdgcn_readfirstlane(blockIdx.x * 4 + wid);
    const __half2* hv = (const __half2*)hp;

    // Independent loads FIRST (R21): overlap the rowptr->esrc scalar chain.
    float di = dinv[node];                      // wave-uniform scalar load
    float2 self = __half22float2(hv[node * 32 + c]);   // pre-scaled h'
    float2 bb = ((const float2*)b)[c];

    float wcol[POOL ? 1 : 64];                  // W column for this lane
    if (!POOL) {
#pragma unroll
        for (int k = 0; k < 64; ++k) wcol[k] = Wnext[k * HD + lane];  // L2-hot
    }

    int s = rowptr[node], e = rowptr[node + 1];     // scalar loads
    float2 acc = {0.f, 0.f};
    int j = s;
    for (; j + 8 <= e; j += 8) {                // unmasked full batches
        int t0 = esrc[j + 0], t1 = esrc[j + 1], t2 = esrc[j + 2], t3 = esrc[j + 3];
        int t4 = esrc[j + 4], t5 = esrc[j + 5], t6 = esrc[j + 6], t7 = esrc[j + 7];
        int a0 = p ? t1 : t0;
        int a1 = p ? t3 : t2;
        int a2 = p ? t5 : t4;
        int a3 = p ? t7 : t6;
        float2 f0 = __half22float2(hv[a0 * 32 + c]);
        float2 f1 = __half22float2(hv[a1 * 32 + c]);
        float2 f2 = __half22float2(hv[a2 * 32 + c]);
        float2 f3 = __half22float2(hv[a3 * 32 + c]);
        acc.x += (f0.x + f1.x) + (f2.x + f3.x);
        acc.y += (f0.y + f1.y) + (f2.y + f3.y);
    }
    if (j < e) {                                // ONE masked batch (rem 1..7)
        // overrun reads stay in allocated memory (esrc padded +64); &0xFFFF
        // bounds any garbage; invalid lanes clamp to t0 (real edge, j < e)
        // and are zero-multiplied — garbage never reaches a gather address.
        int t0 = esrc[j + 0] & 0xFFFF, t1 = esrc[j + 1] & 0xFFFF;
        int t2 = esrc[j + 2] & 0xFFFF, t3 = esrc[j + 3] & 0xFFFF;
        int t4 = esrc[j + 4] & 0xFFFF, t5 = esrc[j + 5] & 0xFFFF;
        int t6 = esrc[j + 6] & 0xFFFF, t7 = esrc[j + 7] & 0xFFFF;
        int i0 = j + p, i1 = j + 2 + p, i2 = j + 4 + p, i3 = j + 6 + p;
        int a0 = p ? t1 : t0;
        int a1 = p ? t3 : t2;
        int a2 = p ? t5 : t4;
        int a3 = p ? t7 : t6;
        a0 = (i0 < e) ? a0 : t0;
        a1 = (i1 < e) ? a1 : t0;
        a2 = (i2 < e) ? a2 : t0;
        a3 = (i3 < e) ? a3 : t0;
        float m0 = (i0 < e) ? 1.f : 0.f;
        float m1 = (i1 < e) ? 1.f : 0.f;
        float m2 = (i2 < e) ? 1.f : 0.f;
        float m3 = (i3 < e) ? 1.f : 0.f;
        float2 f0 = __half22float2(hv[a0 * 32 + c]);
        float2 f1 = __half22float2(hv[a1 * 32 + c]);
        float2 f2 = __half22float2(hv[a2 * 32 + c]);
        float2 f3 = __half22float2(hv[a3 * 32 + c]);
        acc.x += m0 * f0.x + m1 * f1.x + m2 * f2.x + m3 * f3.x;
        acc.y += m0 * f0.y + m1 * f1.y + m2 * f2.y + m3 * f3.y;
    }
    // combine the two edge-pair partials (lane L ^ 32 holds same channel)
    acc.x += __shfl_xor(acc.x, 32, 64);
    acc.y += __shfl_xor(acc.y, 32, 64);

    if (POOL) {
        if (p == 0) {
            float vx = di * (acc.x + self.x) + bb.x;
            float vy = di * (acc.y + self.y) + bb.y;
            int g = batch[node];
            atomicAdd(&pooled[g * HD + 2 * c], vx);
            atomicAdd(&pooled[g * HD + 2 * c + 1], vy);
        }
    } else {
        if (p == 0) {                           // o = dinv*(acc+self)+b; relu
            rowbuf[wid][2 * c]     = fmaxf(di * (acc.x + self.x) + bb.x, 0.f);
            rowbuf[wid][2 * c + 1] = fmaxf(di * (acc.y + self.y) + bb.y, 0.f);
        }
        // same-wave LDS write->read; compiler inserts lgkmcnt wait. No cross-
        // wave hazard: rowbuf slice is private to this wave.
        float outc = 0.f;
        const float4* rb4 = (const float4*)&rowbuf[wid][0];
#pragma unroll
        for (int jj = 0; jj < 16; ++jj) {       // 16 broadcast b128 reads
            float4 r = rb4[jj];
            outc += r.x * wcol[4 * jj + 0] + r.y * wcol[4 * jj + 1]
                  + r.z * wcol[4 * jj + 2] + r.w * wcol[4 * jj + 3];
        }
        hnext[(size_t)node * HD + lane] = __float2half(di * outc);
    }
}

// out[g] = (pooled[g,:]/max(cnt,1)) . lin_W + lin_b   — one wave per graph
__global__ __launch_bounds__(64) void final_kernel(const float* __restrict__ pooled,
                                                   const int* __restrict__ beg,
                                                   const int* __restrict__ endx,
                                                   const float* __restrict__ lin_W,
                                                   const float* __restrict__ lin_b,
                                                   float* __restrict__ out) {
    int g = blockIdx.x, d = threadIdx.x;
    float cnt = (float)(endx[g] - beg[g]);
    float v = pooled[g * HD + d] / fmaxf(cnt, 1.f) * lin_W[d];
#pragma unroll
    for (int off = 32; off > 0; off >>= 1) v += __shfl_down(v, off, 64);
    if (d == 0) out[g] = v + lin_b[0];
}

// ---------------------------------------------------------------------------
extern "C" void kernel_launch(void* const* d_in, const int* in_sizes, int n_in,
                              void* d_out, int out_size, void* d_ws, size_t ws_size,
                              hipStream_t stream) {
    const float* x     = (const float*)d_in[0];
    const float* W1    = (const float*)d_in[1];
    const float* b1    = (const float*)d_in[2];
    const float* W2    = (const float*)d_in[3];
    const float* b2    = (const float*)d_in[4];
    const float* W3    = (const float*)d_in[5];
    const float* b3    = (const float*)d_in[6];
    const float* lin_W = (const float*)d_in[7];
    const float* lin_b = (const float*)d_in[8];
    const int* edge_index = (const int*)d_in[9];   // [2, NE]: row then col
    const int* batch      = (const int*)d_in[10];
    const int* row = edge_index;
    const int* col = edge_index + NE;
    float* out = (float*)d_out;

    // workspace layout (4B units):
    // [h16a NN*HD half][h16b NN*HD half][esrc NE+64][packed NE]
    // [counts M_CNT][rowptr NN+2][dinv NN][pooled NG*HD][beg NG][endx NG]
    __half*   h16a      = (__half*)d_ws;
    __half*   h16b      = h16a + (size_t)NN * HD;
    int*      esrc      = (int*)(h16b + (size_t)NN * HD);
    unsigned* packed    = (unsigned*)(esrc + NE + 64);
    int*      counts    = (int*)(packed + NE);
    int*      rowptr    = counts + M_CNT;
    float*    dinv      = (float*)(rowptr + NN + 2);
    float*    pooled    = (float*)(dinv + NN);
    int*      beg       = (int*)(pooled + NG * HD);
    int*      endx      = beg + NG;

    // count -> {gemm1 || scatter(self-scan)} -> csr_build(self-scan)
    //  -> 3 gathers -> final.  7 launches, no scan kernels, no memsets.
    bucket_count<<<NBL, 256, 0, stream>>>(col, batch, counts, beg, endx, pooled);
    gemm1_scatter<<<GEMM_BLOCKS + NBL, 256, 0, stream>>>(x, W1, h16a, row, col,
                                                         counts, packed);
    csr_build<<<NBK, 256, 0, stream>>>(packed, counts, rowptr, dinv,
                                       h16a, esrc);

    const int GB = NN / 4;  // gather blocks: 4 nodes (waves) each

    // Layer 1 aggregate + fused GEMM2: h16a(=h1') -> h16b(=h2')
    gather_fx<false><<<GB, 256, 0, stream>>>(h16a, rowptr, esrc, dinv, b1, W2,
                                             h16b, batch, pooled);
    // Layer 2 aggregate + fused GEMM3: h16b(=h2') -> h16a(=h3')
    gather_fx<false><<<GB, 256, 0, stream>>>(h16b, rowptr, esrc, dinv, b2, W3,
                                             h16a, batch, pooled);
    // Layer 3 aggregate -> pooled (fused)
    gather_fx<true><<<GB, 256, 0, stream>>>(h16a, rowptr, esrc, dinv, b3, nullptr,
                                            nullptr, batch, pooled);

    final_kernel<<<NG, 64, 0, stream>>>(pooled, beg, endx, lin_W, lin_b, out);
}